// Round 1
// baseline (160.465 us; speedup 1.0000x reference)
//
#include <hip/hip_runtime.h>

#define NN 512   // N
#define DD 16    // D (16 floats = 4 float4)

typedef __attribute__((ext_vector_type(4))) float f32x4;

// One block per (b, i) output row. Block = 512 threads (8 waves).
// v2: NO message staging — per-batch messages are 32 KiB (L1-resident),
// so we read them directly in the store loop (neighbor indices are nearly
// consecutive -> coalesced 16B/lane L1 hits). This removes the per-block
// {32 KiB global->LDS stage + vmcnt(0) drain + barrier} serial phase that
// kept the store pipe idle. LDS: 4 KiB (coef row + compacted indices).
__global__ __launch_bounds__(512) void graph_layer_kernel(
    const int*    __restrict__ adj,    // [B][N][N] int32
    const float*  __restrict__ coef,   // [B][N][N] fp32
    const float4* __restrict__ msg4,   // [B][N][4] (= [B][N][16] fp32)
    float4*       __restrict__ out4)   // [B][N][N*4] (= [B][N][N*16] fp32)
{
    __shared__ float scoef[NN];        // 2 KiB
    __shared__ int   snb[NN];          // compacted valid-column indices
    __shared__ int   wtot[8];          // per-wave valid counts

    const int row  = blockIdx.x;       // b*N + i
    const int b    = row >> 9;
    const int i    = row & (NN - 1);
    const int t    = threadIdx.x;
    const int lane = t & 63;
    const int wv   = t >> 6;

    // --- stage coef row (coalesced; shares the compaction barrier) ---
    scoef[t] = coef[(size_t)row * NN + t];

    // --- general neighbor compaction: sort(where(valid, cols, n))[:n-1] ---
    // stable ascending compaction of valid columns; fill = n clamped to n-1
    const int  a     = adj[(size_t)row * NN + t];
    const bool valid = (a != -1);
    const unsigned long long m = __ballot(valid);
    const int  rank  = __popcll(m & ((1ULL << lane) - 1ULL));
    snb[t] = NN - 1;                   // JAX out-of-bounds gather clamps n -> n-1
    if (lane == 0) wtot[wv] = __popcll(m);
    __syncthreads();

    int base = 0;
    #pragma unroll
    for (int w = 0; w < 8; ++w)
        base += (w < wv) ? wtot[w] : 0;
    if (valid) {
        const int pos = base + rank;
        if (pos < NN) snb[pos] = t;
    }
    __syncthreads();

    // --- produce the output row: 8192 floats = 2048 float4, coalesced ---
    // Messages read directly from global: per-batch footprint is 32 KiB,
    // L1/L2-resident; snb values are nearly consecutive so lanes read
    // ~contiguous 16B chunks. Stores are non-temporal (streaming, never
    // re-read; don't allocate 128 MiB through L2).
    const float4* mb   = msg4 + (size_t)b * (NN * 4);
    float4*       orow = out4 + (size_t)row * (NN * 4);
    #pragma unroll
    for (int k = 0; k < 4; ++k) {
        const int g = t + k * 512;     // float4 index within the row
        const int j = g >> 2;          // output column (which neighbor slot)
        const int q = g & 3;           // which float4 of the D=16 message
        const int s = (j == 0) ? i : snb[j - 1];
        const float c = scoef[j];
        const float4 v = mb[s * 4 + q];
        f32x4 o = { c * v.x, c * v.y, c * v.z, c * v.w };
        __builtin_nontemporal_store(o, (f32x4*)&orow[g]);
    }
}

extern "C" void kernel_launch(void* const* d_in, const int* in_sizes, int n_in,
                              void* d_out, int out_size, void* d_ws, size_t ws_size,
                              hipStream_t stream) {
    const int*    adj  = (const int*)d_in[0];     // adj_matrix (int32)
    const float*  coef = (const float*)d_in[1];   // adj_coef
    const float4* msg4 = (const float4*)d_in[2];  // neighbour_messages
    float4*       out4 = (float4*)d_out;          // fp32 output

    const int B = 8;
    graph_layer_kernel<<<B * NN, 512, 0, stream>>>(adj, coef, msg4, out4);
}